// Round 1
// 333.296 us; speedup vs baseline: 1.0712x; 1.0712x over previous
//
#include <hip/hip_runtime.h>

#define LEVELS 16
#define TSIZE 524288
#define TMASK (TSIZE - 1)
#define TPB 256
#define GPPT 8                  // gather: points per thread
#define CHUNK (TPB * GPPT)      // 2048 points per chunk/slab

typedef float f2v __attribute__((ext_vector_type(2)));
typedef float f4v __attribute__((ext_vector_type(4)));

// int(16 * 1.5**l), exact as float32
__device__ __constant__ float c_res[LEVELS] = {
    16.f, 24.f, 36.f, 54.f, 81.f, 121.f, 182.f, 273.f,
    410.f, 615.f, 922.f, 1383.f, 2075.f, 3113.f, 4670.f, 7006.f
};

__device__ __forceinline__ unsigned hash_idx(float px, float py, float pz, float r)
{
    const int ix = (int)floorf(px * r);
    const int iy = (int)floorf(py * r);
    const int iz = (int)floorf(pz * r);
    const unsigned h = (unsigned)ix * 73856093u
                     ^ (unsigned)iy * 19349663u
                     ^ (unsigned)iz * 83492791u;
    return h & TMASK;
}

// ws layout: chunk-tiled slabs  ws[(c*LEVELS + l)*CHUNK + local]
// -> a chunk's 16 level slabs are contiguous (16KB apart, 256KB window):
//    kills the 16MiB power-of-two stream spacing that caused channel camping.

// ---------------- Kernel A: XCD-pinned level-major gather --------------------
// grid = 2 halves x 8 x bpl. Block b: level = half*8 + (b%8).
// Round-robin dispatch puts b%8==k on XCD k -> each XCD's 4MB L2 serves one
// 4MB table per half (round-5-proven: FETCH 1.9GB -> 0.55GB vs naive).
//
// Round-6: full-chunk fast path with NO per-point guards, explicitly phased
// loads -> hashes -> 8 independent random gathers in flight -> stores.
// The guarded per-j structure kept ~1 divergent gather outstanding per wave
// (latency-bound at ~293 cyc/wave-iter); this restores 8-deep MLP.
__global__ __launch_bounds__(TPB) void gather_kernel(
    const float* __restrict__ x,
    const float* __restrict__ tables,
    f2v* __restrict__ ws,
    int n, int bpl)
{
    const int b = blockIdx.x;
    const int half = b / (8 * bpl);
    const int r = b % (8 * bpl);
    const int level = half * 8 + (r & 7);
    const int c = r >> 3;                   // chunk id
    const int t = threadIdx.x;

    const float rs = c_res[level];
    const float* __restrict__ tbl = tables + (size_t)level * (TSIZE * 2);
    f2v* __restrict__ slab = ws + ((size_t)c * LEVELS + level) * CHUNK;
    const long long base = (long long)c * CHUNK;

    if (base + CHUNK <= n) {
        // -------- fast path: full chunk, phase-batched for deep MLP --------
        const float* __restrict__ xb = x + 3 * base;

        float px[GPPT], py[GPPT], pz[GPPT];
#pragma unroll
        for (int j = 0; j < GPPT; ++j) {
            const int local = j * TPB + t;
            px[j] = xb[3 * local + 0];
            py[j] = xb[3 * local + 1];
            pz[j] = xb[3 * local + 2];
        }

        unsigned idx[GPPT];
#pragma unroll
        for (int j = 0; j < GPPT; ++j)
            idx[j] = hash_idx(px[j], py[j], pz[j], rs);

        // 8 independent random 8B gathers in flight (all hit XCD-local L2)
        f2v e[GPPT];
#pragma unroll
        for (int j = 0; j < GPPT; ++j)
            e[j] = *reinterpret_cast<const f2v*>(tbl + 2 * (size_t)idx[j]);

#pragma unroll
        for (int j = 0; j < GPPT; ++j)
            __builtin_nontemporal_store(e[j], slab + j * TPB + t);
    } else {
        // -------- tail path: original guarded loop --------
#pragma unroll
        for (int j = 0; j < GPPT; ++j) {
            const int local = j * TPB + t;
            const long long p = base + local;
            if (p < n) {
                const float qx = x[3 * p + 0];
                const float qy = x[3 * p + 1];
                const float qz = x[3 * p + 2];
                const unsigned idx = hash_idx(qx, qy, qz, rs);
                const f2v e = *reinterpret_cast<const f2v*>(tbl + 2 * (size_t)idx);
                __builtin_nontemporal_store(e, slab + local);
            }
        }
    }
}

// ---------------- Kernel B: assemble (slab ws -> point-major out rows) -------
// Block = one 2048-point chunk. Lane q=t&7 supplies quads 4q..4q+3 (levels
// 2q,2q+1). Round-6: guard hoisted + f4v-widened (each lane handles 2 points
// per iter: one 16B load per slab, two 16B row stores) -> half the VMEM
// instruction count at identical traffic.
__global__ __launch_bounds__(TPB) void assemble_kernel(
    const f2v* __restrict__ ws,
    float* __restrict__ out,
    int n)
{
    const int c = blockIdx.x;
    const int t = threadIdx.x;
    const int q = t & 7;
    const int sub = t >> 3;  // 0..31

    const f2v* __restrict__ wa = ws + ((size_t)c * LEVELS + 2 * q) * CHUNK;
    const f2v* __restrict__ wb = wa + CHUNK;
    const long long base = (long long)c * CHUNK;

    if (base + CHUNK <= n) {
        // fast path: 2 points per lane per iter, no guards
#pragma unroll 8
        for (int u = 0; u < CHUNK / 64; ++u) {
            const int lp = 2 * (u * 32 + sub);
            const f4v a = __builtin_nontemporal_load(
                reinterpret_cast<const f4v*>(wa + lp));
            const f4v b = __builtin_nontemporal_load(
                reinterpret_cast<const f4v*>(wb + lp));
            f4v v0, v1;
            v0.x = a.x; v0.y = a.y; v0.z = b.x; v0.w = b.y;
            v1.x = a.z; v1.y = a.w; v1.z = b.z; v1.w = b.w;
            float* row = out + (size_t)(base + lp) * (2 * LEVELS) + 4 * q;
            __builtin_nontemporal_store(v0, reinterpret_cast<f4v*>(row));
            __builtin_nontemporal_store(v1, reinterpret_cast<f4v*>(row + 2 * LEVELS));
        }
    } else {
        // tail path: original guarded loop
#pragma unroll 8
        for (int u = 0; u < CHUNK / 32; ++u) {
            const int lp = u * 32 + sub;
            const long long pt = base + lp;
            if (pt < n) {
                const f2v a = __builtin_nontemporal_load(wa + lp);
                const f2v b = __builtin_nontemporal_load(wb + lp);
                f4v v;
                v.x = a.x; v.y = a.y; v.z = b.x; v.w = b.y;
                __builtin_nontemporal_store(
                    v, reinterpret_cast<f4v*>(out + (size_t)pt * (2 * LEVELS) + 4 * q));
            }
        }
    }
}

// ---------------- Fallback (ws too small): round-3 fused kernel --------------
#define ROWW 34
__global__ __launch_bounds__(TPB) void hashgrid_fused(
    const float* __restrict__ x,
    const float* __restrict__ tables,
    float* __restrict__ out,
    int n)
{
    __shared__ float lds[TPB * ROWW];
    const int t = threadIdx.x;

    for (long long base = (long long)blockIdx.x * TPB; base < n;
         base += (long long)gridDim.x * TPB) {
        const int p = (int)base + t;
        float px = 0.f, py = 0.f, pz = 0.f;
        if (p < n) {
            px = x[3 * (size_t)p + 0];
            py = x[3 * (size_t)p + 1];
            pz = x[3 * (size_t)p + 2];
        }
#pragma unroll
        for (int l = 0; l < LEVELS; ++l) {
            if (p < n) {
                const unsigned idx = hash_idx(px, py, pz, c_res[l]);
                const f2v e = *reinterpret_cast<const f2v*>(
                    tables + (((size_t)l * TSIZE + idx) << 1));
                *reinterpret_cast<f2v*>(lds + t * ROWW + 2 * l) = e;
            }
            __syncthreads();
        }
#pragma unroll
        for (int it = 0; it < 8; ++it) {
            const int lp = it * 32 + (t >> 3);
            const int qq = t & 7;
            const int gp = (int)base + lp;
            if (gp < n) {
                const f2v a = *reinterpret_cast<const f2v*>(lds + lp * ROWW + 4 * qq);
                const f2v b = *reinterpret_cast<const f2v*>(lds + lp * ROWW + 4 * qq + 2);
                f4v v;
                v.x = a.x; v.y = a.y; v.z = b.x; v.w = b.y;
                __builtin_nontemporal_store(
                    v, reinterpret_cast<f4v*>(out + (size_t)gp * (2 * LEVELS) + 4 * qq));
            }
        }
        __syncthreads();
    }
}

extern "C" void kernel_launch(void* const* d_in, const int* in_sizes, int n_in,
                              void* d_out, int out_size, void* d_ws, size_t ws_size,
                              hipStream_t stream)
{
    const float* x      = (const float*)d_in[0];   // [N, 3]
    const float* tables = (const float*)d_in[1];   // [L, T, F]
    float* out          = (float*)d_out;           // [N, L*F]
    const int n = in_sizes[0] / 3;

    const int bpl = (n + CHUNK - 1) / CHUNK;       // chunks (= blocks per level)
    const size_t ws_need = (size_t)bpl * LEVELS * CHUNK * sizeof(f2v);
    if (ws_size < ws_need) {
        int grid = 1024;
        const int nblocks = (n + TPB - 1) / TPB;
        if (nblocks < grid) grid = nblocks;
        hashgrid_fused<<<grid, TPB, 0, stream>>>(x, tables, out, n);
        return;
    }

    f2v* ws = (f2v*)d_ws;
    gather_kernel<<<2 * 8 * bpl, TPB, 0, stream>>>(x, tables, ws, n, bpl);
    assemble_kernel<<<bpl, TPB, 0, stream>>>(ws, out, n);
}